// Round 3
// baseline (217.739 us; speedup 1.0000x reference)
//
#include <hip/hip_runtime.h>
#include <math.h>

#define S_LEN 1024
#define D_DIM 64
#define NBH   16

typedef unsigned short ushort_t;
typedef __attribute__((ext_vector_type(8))) short short8;   // 8 bf16 (4 VGPRs)
typedef __attribute__((ext_vector_type(4))) short short4v;  // 4 bf16 (8 B)
typedef __attribute__((ext_vector_type(4))) float f32x4;

// fp32 -> (hi, lo) bf16 pair, round-to-nearest-even.
__device__ __forceinline__ void split1(float x, ushort_t& h, ushort_t& l) {
    unsigned u = __float_as_uint(x);
    unsigned hh = (u + 0x7FFFu + ((u >> 16) & 1u)) >> 16;
    float hf = __uint_as_float(hh << 16);
    float lf = x - hf;
    unsigned ul = __float_as_uint(lf);
    unsigned hl = (ul + 0x7FFFu + ((ul >> 16) & 1u)) >> 16;
    h = (ushort_t)hh; l = (ushort_t)hl;
}

// ---------------- Prep A: split Q and K into bf16 hi/lo (same layout) --------
// 1M floats each; one thread = one float4. grid = 2*1M/4/256 = 2048 blocks.
__global__ __launch_bounds__(256) void split_qk(const float* __restrict__ q,
                                                const float* __restrict__ k,
                                                ushort_t* __restrict__ qhi, ushort_t* __restrict__ qlo,
                                                ushort_t* __restrict__ khi, ushort_t* __restrict__ klo) {
    const int NV = (NBH * S_LEN * D_DIM) / 4;     // 262144 float4 per tensor
    int idx = blockIdx.x * 256 + threadIdx.x;     // 0 .. 2*NV-1
    const bool isq = idx < NV;
    const int i4 = isq ? idx : idx - NV;
    const float* src = isq ? q : k;
    float4 x = *(const float4*)(src + (size_t)i4 * 4);
    ushort_t h[4], l[4];
    split1(x.x, h[0], l[0]); split1(x.y, h[1], l[1]);
    split1(x.z, h[2], l[2]); split1(x.w, h[3], l[3]);
    ushort_t* dh = (isq ? qhi : khi) + (size_t)i4 * 4;
    ushort_t* dl = (isq ? qlo : klo) + (size_t)i4 * 4;
    short4v hv = {(short)h[0], (short)h[1], (short)h[2], (short)h[3]};
    short4v lv = {(short)l[0], (short)l[1], (short)l[2], (short)l[3]};
    *(short4v*)dh = hv;
    *(short4v*)dl = lv;
}

// ---------------- Prep B: transpose V[t][d] -> Vt[d][t], split to bf16 -------
// grid (16 t-tiles, 16 bh), block 256. 64x64 tile through LDS.
__global__ __launch_bounds__(256) void vprep(const float* __restrict__ v,
                                             ushort_t* __restrict__ vthi,
                                             ushort_t* __restrict__ vtlo) {
    __shared__ float Ls[64][65];
    const int tt = blockIdx.x, bh = blockIdx.y;
    const int tid = threadIdx.x;
    const float* vb = v + ((size_t)bh * S_LEN + tt * 64) * D_DIM;
    #pragma unroll
    for (int p = 0; p < 4; ++p) {
        int idx = p * 1024 + tid * 4;             // elem in 64x64 tile
        int r = idx >> 6, c = idx & 63;
        float4 x = *(const float4*)(vb + r * 64 + c);
        Ls[r][c] = x.x; Ls[r][c+1] = x.y; Ls[r][c+2] = x.z; Ls[r][c+3] = x.w;
    }
    __syncthreads();
    const int d = tid >> 2, c0 = (tid & 3) * 16;
    ushort_t hi[16], lo[16];
    #pragma unroll
    for (int j = 0; j < 16; ++j) split1(Ls[c0 + j][d], hi[j], lo[j]);
    size_t ob = ((size_t)bh * D_DIM + d) * S_LEN + tt * 64 + c0;
    *(short8*)(vthi + ob)     = *(short8*)(hi);
    *(short8*)(vthi + ob + 8) = *(short8*)(hi + 8);
    *(short8*)(vtlo + ob)     = *(short8*)(lo);
    *(short8*)(vtlo + ob + 8) = *(short8*)(lo + 8);
}

// --------- Kernel 1: dp[bh,s,t] = (1/8) * sum_d Q[bh,s,d]*K[bh,t,d] (MFMA) ---
// grid (64 s-tiles, 16 bh), 4 waves; wave w covers t in [w*256, w*256+256)
__global__ __launch_bounds__(256) void qk_mfma(const ushort_t* __restrict__ qhi,
                                               const ushort_t* __restrict__ qlo,
                                               const ushort_t* __restrict__ khi,
                                               const ushort_t* __restrict__ klo,
                                               float* __restrict__ dp) {
    const int st = blockIdx.x, bh = blockIdx.y;
    const int tid = threadIdx.x;
    const int wave = tid >> 6, lane = tid & 63;
    const int m = lane & 15, quad = lane >> 4;

    const size_t abase = ((size_t)bh * S_LEN + st * 16 + m) * D_DIM + quad * 8;
    short8 ahi0 = *(const short8*)(qhi + abase);
    short8 ahi1 = *(const short8*)(qhi + abase + 32);
    short8 alo0 = *(const short8*)(qlo + abase);
    short8 alo1 = *(const short8*)(qlo + abase + 32);

    const size_t kbase = ((size_t)bh * S_LEN + m) * D_DIM + quad * 8;
    float* dpb = dp + (size_t)bh * S_LEN * S_LEN;

    for (int tt = 0; tt < 16; ++tt) {
        const int t0 = wave * 256 + tt * 16;
        const size_t kb = kbase + (size_t)t0 * D_DIM;
        short8 bhi0 = *(const short8*)(khi + kb);
        short8 bhi1 = *(const short8*)(khi + kb + 32);
        short8 blo0 = *(const short8*)(klo + kb);
        short8 blo1 = *(const short8*)(klo + kb + 32);

        f32x4 acc = {0.f, 0.f, 0.f, 0.f};
        acc = __builtin_amdgcn_mfma_f32_16x16x32_bf16(ahi0, bhi0, acc, 0, 0, 0);
        acc = __builtin_amdgcn_mfma_f32_16x16x32_bf16(ahi0, blo0, acc, 0, 0, 0);
        acc = __builtin_amdgcn_mfma_f32_16x16x32_bf16(alo0, bhi0, acc, 0, 0, 0);
        acc = __builtin_amdgcn_mfma_f32_16x16x32_bf16(ahi1, bhi1, acc, 0, 0, 0);
        acc = __builtin_amdgcn_mfma_f32_16x16x32_bf16(ahi1, blo1, acc, 0, 0, 0);
        acc = __builtin_amdgcn_mfma_f32_16x16x32_bf16(alo1, bhi1, acc, 0, 0, 0);

        // C/D: col = lane&15 (t), row = quad*4 + r (s)
        #pragma unroll
        for (int r = 0; r < 4; ++r)
            dpb[(size_t)(st * 16 + quad * 4 + r) * S_LEN + t0 + m] = acc[r] * 0.125f;
    }
}

// ------------- Kernel 2: fused conv(3x3,4f)+leaky+linear+mask+softmax --------
// writes attn as bf16 hi/lo pair
__global__ __launch_bounds__(256) void conv_softmax_kernel(
    const float* __restrict__ dp, const int* __restrict__ mask,
    const float* __restrict__ conv_w, const float* __restrict__ conv_b,
    const float* __restrict__ lin_w, const float* __restrict__ lin_b,
    ushort_t* __restrict__ attn_hi, ushort_t* __restrict__ attn_lo) {
    __shared__ float rows[3][S_LEN];
    __shared__ float red[8];
    const int s  = blockIdx.x;
    const int bh = blockIdx.y;
    const int b  = bh >> 3;
    const int tid = threadIdx.x;
    const float* base = dp + (size_t)bh * S_LEN * S_LEN;

    float cen[3][4];
    #pragma unroll
    for (int r = 0; r < 3; ++r) {
        int sr = s - 1 + r;
        float4 val;
        if (sr >= 0 && sr < S_LEN)
            val = *(const float4*)(base + (size_t)sr * S_LEN + tid * 4);
        else
            val = make_float4(0.f, 0.f, 0.f, 0.f);
        cen[r][0] = val.x; cen[r][1] = val.y; cen[r][2] = val.z; cen[r][3] = val.w;
        ((float4*)rows[r])[tid] = val;
    }
    __syncthreads();

    float lft[3], rgt[3];
    #pragma unroll
    for (int r = 0; r < 3; ++r) {
        lft[r] = (tid > 0)   ? rows[r][tid * 4 - 1] : 0.f;
        rgt[r] = (tid < 255) ? rows[r][tid * 4 + 4] : 0.f;
    }

    float w[4][9];
    #pragma unroll
    for (int f = 0; f < 4; ++f)
        #pragma unroll
        for (int i = 0; i < 9; ++i) w[f][i] = conv_w[f * 9 + i];
    float cb[4], lw[4];
    #pragma unroll
    for (int f = 0; f < 4; ++f) { cb[f] = conv_b[f]; lw[f] = lin_w[f]; }
    const float lb = lin_b[0];
    const int* mrow = mask + ((size_t)b * S_LEN + s) * S_LEN;
    const int4 mv = *(const int4*)(mrow + tid * 4);
    const int mk[4] = {mv.x, mv.y, mv.z, mv.w};

    float p[4];
    #pragma unroll
    for (int c = 0; c < 4; ++c) {
        float v[9];
        #pragma unroll
        for (int di = 0; di < 3; ++di) {
            v[di*3+0] = (c == 0) ? lft[di] : cen[di][c-1];
            v[di*3+1] = cen[di][c];
            v[di*3+2] = (c == 3) ? rgt[di] : cen[di][c+1];
        }
        float acc = lb;
        #pragma unroll
        for (int f = 0; f < 4; ++f) {
            float cv = cb[f];
            #pragma unroll
            for (int i = 0; i < 9; ++i) cv = fmaf(w[f][i], v[i], cv);
            float act = cv > 0.f ? cv : 0.01f * cv;
            acc = fmaf(lw[f], act, acc);
        }
        p[c] = (mk[c] == 0) ? -1e30f : acc;
    }

    float mx = fmaxf(fmaxf(p[0], p[1]), fmaxf(p[2], p[3]));
    #pragma unroll
    for (int off = 32; off > 0; off >>= 1) mx = fmaxf(mx, __shfl_down(mx, off));
    const int lane = tid & 63, wid = tid >> 6;
    if (lane == 0) red[wid] = mx;
    __syncthreads();
    const float rowmax = fmaxf(fmaxf(red[0], red[1]), fmaxf(red[2], red[3]));

    float e[4], ls = 0.f;
    #pragma unroll
    for (int c = 0; c < 4; ++c) { e[c] = __expf(p[c] - rowmax); ls += e[c]; }
    #pragma unroll
    for (int off = 32; off > 0; off >>= 1) ls += __shfl_down(ls, off);
    if (lane == 0) red[4 + wid] = ls;
    __syncthreads();
    const float inv = 1.0f / (red[4] + red[5] + red[6] + red[7]);

    ushort_t h[4], l[4];
    #pragma unroll
    for (int c = 0; c < 4; ++c) split1(e[c] * inv, h[c], l[c]);
    short4v hv = {(short)h[0], (short)h[1], (short)h[2], (short)h[3]};
    short4v lv = {(short)l[0], (short)l[1], (short)l[2], (short)l[3]};
    const size_t ob = ((size_t)bh * S_LEN + s) * S_LEN + tid * 4;
    *(short4v*)(attn_hi + ob) = hv;
    *(short4v*)(attn_lo + ob) = lv;
}

// --------- Kernel 3: out[bh,s,d] = sum_t attn[bh,s,t]*V[bh,t,d] (MFMA) -------
// grid (64 s-tiles, 16 bh), 4 waves; wave w handles d-tile d0 = w*16
__global__ __launch_bounds__(256) void av_mfma(const ushort_t* __restrict__ attn_hi,
                                               const ushort_t* __restrict__ attn_lo,
                                               const ushort_t* __restrict__ vthi,
                                               const ushort_t* __restrict__ vtlo,
                                               float* __restrict__ out) {
    const int st = blockIdx.x, bh = blockIdx.y;
    const int tid = threadIdx.x;
    const int wave = tid >> 6, lane = tid & 63;
    const int m = lane & 15, quad = lane >> 4;
    const int d0 = wave * 16;

    const size_t arow = ((size_t)bh * S_LEN + st * 16 + m) * S_LEN + quad * 8;
    const size_t vrow = ((size_t)bh * D_DIM + d0 + m) * S_LEN + quad * 8;

    f32x4 acc = {0.f, 0.f, 0.f, 0.f};
    for (int t0 = 0; t0 < S_LEN; t0 += 32) {
        short8 ahi = *(const short8*)(attn_hi + arow + t0);
        short8 alo = *(const short8*)(attn_lo + arow + t0);
        short8 bhi = *(const short8*)(vthi + vrow + t0);
        short8 blo = *(const short8*)(vtlo + vrow + t0);
        acc = __builtin_amdgcn_mfma_f32_16x16x32_bf16(ahi, bhi, acc, 0, 0, 0);
        acc = __builtin_amdgcn_mfma_f32_16x16x32_bf16(alo, bhi, acc, 0, 0, 0);
        acc = __builtin_amdgcn_mfma_f32_16x16x32_bf16(ahi, blo, acc, 0, 0, 0);
    }

    // C/D: col = lane&15 (d), row = quad*4 + r (s)
    #pragma unroll
    for (int r = 0; r < 4; ++r)
        out[((size_t)bh * S_LEN + st * 16 + quad * 4 + r) * D_DIM + d0 + m] = acc[r];
}

extern "C" void kernel_launch(void* const* d_in, const int* in_sizes, int n_in,
                              void* d_out, int out_size, void* d_ws, size_t ws_size,
                              hipStream_t stream) {
    const float* q      = (const float*)d_in[0];
    const float* k      = (const float*)d_in[1];
    const float* v      = (const float*)d_in[2];
    const int*   mask   = (const int*)d_in[3];
    const float* conv_w = (const float*)d_in[4];
    const float* conv_b = (const float*)d_in[5];
    const float* lin_w  = (const float*)d_in[6];
    const float* lin_b  = (const float*)d_in[7];
    float* out = (float*)d_out;

    // workspace layout (bytes):
    //   dp        fp32  64 MiB   @ 0
    //   attn_hi   bf16  32 MiB   @ 64 MiB
    //   attn_lo   bf16  32 MiB   @ 96 MiB
    //   qhi/qlo/khi/klo  2 MiB each @ 128..136 MiB
    //   vthi/vtlo        2 MiB each @ 136..140 MiB
    char* wsb = (char*)d_ws;
    const size_t MB = 1024 * 1024;
    float*    dp      = (float*)wsb;
    ushort_t* attn_hi = (ushort_t*)(wsb + 64 * MB);
    ushort_t* attn_lo = (ushort_t*)(wsb + 96 * MB);
    ushort_t* qhi     = (ushort_t*)(wsb + 128 * MB);
    ushort_t* qlo     = (ushort_t*)(wsb + 130 * MB);
    ushort_t* khi     = (ushort_t*)(wsb + 132 * MB);
    ushort_t* klo     = (ushort_t*)(wsb + 134 * MB);
    ushort_t* vthi    = (ushort_t*)(wsb + 136 * MB);
    ushort_t* vtlo    = (ushort_t*)(wsb + 138 * MB);

    split_qk<<<dim3(2048), 256, 0, stream>>>(q, k, qhi, qlo, khi, klo);
    vprep<<<dim3(16, NBH), 256, 0, stream>>>(v, vthi, vtlo);
    qk_mfma<<<dim3(64, NBH), 256, 0, stream>>>(qhi, qlo, khi, klo, dp);
    conv_softmax_kernel<<<dim3(S_LEN, NBH), 256, 0, stream>>>(
        dp, mask, conv_w, conv_b, lin_w, lin_b, attn_hi, attn_lo);
    av_mfma<<<dim3(64, NBH), 256, 0, stream>>>(attn_hi, attn_lo, vthi, vtlo, out);
}

// Round 4
// 176.434 us; speedup vs baseline: 1.2341x; 1.2341x over previous
//
#include <hip/hip_runtime.h>
#include <math.h>

#define S_LEN 1024
#define D_DIM 64
#define NBH   16
#define CH    128          // t-chunk width
#define NCH   8            // chunks per row
#define RPB   14           // output rows per block (16-row MFMA tile - 2 halo)
#define NSB   74           // ceil(1024/14)

typedef unsigned short ushort_t;
typedef __attribute__((ext_vector_type(8))) short short8;   // 8 bf16 (4 VGPRs)
typedef __attribute__((ext_vector_type(4))) short short4v;  // 4 bf16 (8 B)
typedef __attribute__((ext_vector_type(4))) float f32x4;

// fp32 -> (hi, lo) bf16 pair, round-to-nearest-even.
__device__ __forceinline__ void split1(float x, ushort_t& h, ushort_t& l) {
    unsigned u = __float_as_uint(x);
    unsigned hh = (u + 0x7FFFu + ((u >> 16) & 1u)) >> 16;
    float hf = __uint_as_float(hh << 16);
    float lf = x - hf;
    unsigned ul = __float_as_uint(lf);
    unsigned hl = (ul + 0x7FFFu + ((ul >> 16) & 1u)) >> 16;
    h = (ushort_t)hh; l = (ushort_t)hl;
}

// ---------------- Prep A: split Q and K into bf16 hi/lo (same layout) --------
__global__ __launch_bounds__(256) void split_qk(const float* __restrict__ q,
                                                const float* __restrict__ k,
                                                ushort_t* __restrict__ qhi, ushort_t* __restrict__ qlo,
                                                ushort_t* __restrict__ khi, ushort_t* __restrict__ klo) {
    const int NV = (NBH * S_LEN * D_DIM) / 4;     // 262144 float4 per tensor
    int idx = blockIdx.x * 256 + threadIdx.x;
    const bool isq = idx < NV;
    const int i4 = isq ? idx : idx - NV;
    const float* src = isq ? q : k;
    float4 x = *(const float4*)(src + (size_t)i4 * 4);
    ushort_t h[4], l[4];
    split1(x.x, h[0], l[0]); split1(x.y, h[1], l[1]);
    split1(x.z, h[2], l[2]); split1(x.w, h[3], l[3]);
    ushort_t* dh = (isq ? qhi : khi) + (size_t)i4 * 4;
    ushort_t* dl = (isq ? qlo : klo) + (size_t)i4 * 4;
    short4v hv = {(short)h[0], (short)h[1], (short)h[2], (short)h[3]};
    short4v lv = {(short)l[0], (short)l[1], (short)l[2], (short)l[3]};
    *(short4v*)dh = hv;
    *(short4v*)dl = lv;
}

// ---------------- Prep B: transpose V[t][d] -> Vt[d][t], split to bf16 -------
__global__ __launch_bounds__(256) void vprep(const float* __restrict__ v,
                                             ushort_t* __restrict__ vthi,
                                             ushort_t* __restrict__ vtlo) {
    __shared__ float Ls[64][65];
    const int tt = blockIdx.x, bh = blockIdx.y;
    const int tid = threadIdx.x;
    const float* vb = v + ((size_t)bh * S_LEN + tt * 64) * D_DIM;
    #pragma unroll
    for (int p = 0; p < 4; ++p) {
        int idx = p * 1024 + tid * 4;
        int r = idx >> 6, c = idx & 63;
        float4 x = *(const float4*)(vb + r * 64 + c);
        Ls[r][c] = x.x; Ls[r][c+1] = x.y; Ls[r][c+2] = x.z; Ls[r][c+3] = x.w;
    }
    __syncthreads();
    const int d = tid >> 2, c0 = (tid & 3) * 16;
    ushort_t hi[16], lo[16];
    #pragma unroll
    for (int j = 0; j < 16; ++j) split1(Ls[c0 + j][d], hi[j], lo[j]);
    size_t ob = ((size_t)bh * D_DIM + d) * S_LEN + tt * 64 + c0;
    *(short8*)(vthi + ob)     = *(short8*)(hi);
    *(short8*)(vthi + ob + 8) = *(short8*)(hi + 8);
    *(short8*)(vtlo + ob)     = *(short8*)(lo);
    *(short8*)(vtlo + ob + 8) = *(short8*)(lo + 8);
}

// ------------------ Fused: QK^T -> conv -> online softmax -> PV --------------
// grid (74 s-tiles, 16 bh), block 256 = 4 waves.
// Buffer rows br=0..15 map to s = s0-1+br; output rows br=1..14.
__global__ __launch_bounds__(256) void fused_attn(
    const ushort_t* __restrict__ qhi, const ushort_t* __restrict__ qlo,
    const ushort_t* __restrict__ khi, const ushort_t* __restrict__ klo,
    const ushort_t* __restrict__ vthi, const ushort_t* __restrict__ vtlo,
    const int* __restrict__ mask,
    const float* __restrict__ conv_w, const float* __restrict__ conv_b,
    const float* __restrict__ lin_w, const float* __restrict__ lin_b,
    float* __restrict__ out)
{
    __shared__ float dpS[3][16][132];        // 3-slot ring of dp chunks (25.3 KB)
    __shared__ ushort_t pHi[4 * 16 * 32];    // P bf16 hi, A-fragment layout (4 KB)
    __shared__ ushort_t pLo[4 * 16 * 32];    // P bf16 lo (4 KB)
    __shared__ float mS[16], lS[16], aS[16];

    const int bs = blockIdx.x, bh = blockIdx.y;
    const int s0 = bs * RPB;
    const int b  = bh >> 3;
    const int tid = threadIdx.x;
    const int wave = tid >> 6, lane = tid & 63;
    const int m = lane & 15, quad = lane >> 4;

    if (tid < 16) { mS[tid] = -1e30f; lS[tid] = 0.f; aS[tid] = 1.f; }

    // conv params (uniform -> SGPRs)
    float w[36];
    #pragma unroll
    for (int i = 0; i < 36; ++i) w[i] = conv_w[i];
    float cb[4], lw[4];
    #pragma unroll
    for (int f = 0; f < 4; ++f) { cb[f] = conv_b[f]; lw[f] = lin_w[f]; }
    const float lb = lin_b[0];

    // A fragments: Q rows s0-1+m (clamped; invalid rows zeroed at conv stage)
    const int sA = s0 - 1 + m;
    const int sQ = sA < 0 ? 0 : (sA > S_LEN - 1 ? S_LEN - 1 : sA);
    const size_t qbase = ((size_t)bh * S_LEN + sQ) * D_DIM + quad * 8;
    const short8 ahi0 = *(const short8*)(qhi + qbase);
    const short8 ahi1 = *(const short8*)(qhi + qbase + 32);
    const short8 alo0 = *(const short8*)(qlo + qbase);
    const short8 alo1 = *(const short8*)(qlo + qbase + 32);

    // conv-phase thread mapping: row rr, col-group cg (8 cols each)
    const int rr = tid >> 4, cg = tid & 15, c0 = cg * 8;
    const bool act = (rr >= 1) && (rr <= RPB) && (s0 - 1 + rr <= S_LEN - 1);

    const int d0 = wave * 16;                // PV: wave handles d-range [d0,d0+16)
    f32x4 O = {0.f, 0.f, 0.f, 0.f};

    for (int j = 0; j <= NCH; ++j) {
        // ---------------- dp chunk j -> slot j%3 (MFMA QK^T) ----------------
        if (j < NCH) {
            const int slot = j % 3;
            #pragma unroll
            for (int ct = 0; ct < 2; ++ct) {
                const int t0 = j * CH + wave * 32 + ct * 16;
                const size_t kb = ((size_t)bh * S_LEN + t0 + m) * D_DIM + quad * 8;
                short8 bhi0 = *(const short8*)(khi + kb);
                short8 bhi1 = *(const short8*)(khi + kb + 32);
                short8 blo0 = *(const short8*)(klo + kb);
                short8 blo1 = *(const short8*)(klo + kb + 32);
                f32x4 acc = {0.f, 0.f, 0.f, 0.f};
                acc = __builtin_amdgcn_mfma_f32_16x16x32_bf16(ahi0, bhi0, acc, 0, 0, 0);
                acc = __builtin_amdgcn_mfma_f32_16x16x32_bf16(ahi0, blo0, acc, 0, 0, 0);
                acc = __builtin_amdgcn_mfma_f32_16x16x32_bf16(alo0, bhi0, acc, 0, 0, 0);
                acc = __builtin_amdgcn_mfma_f32_16x16x32_bf16(ahi1, bhi1, acc, 0, 0, 0);
                acc = __builtin_amdgcn_mfma_f32_16x16x32_bf16(ahi1, blo1, acc, 0, 0, 0);
                acc = __builtin_amdgcn_mfma_f32_16x16x32_bf16(alo1, bhi1, acc, 0, 0, 0);
                const int col = wave * 32 + ct * 16 + m;
                #pragma unroll
                for (int r = 0; r < 4; ++r)
                    dpS[slot][quad * 4 + r][col] = acc[r] * 0.125f;
            }
        }
        __syncthreads();

        if (j >= 1) {
            // ------------- conv + mask + online softmax on chunk c ----------
            const int c = j - 1;
            const int slotC = c % 3;
            const int slotL = (c + 2) % 3;
            const int slotR = (c + 1) % 3;
            const int sub = cg >> 2, qd = cg & 3;
            ushort_t* dsth = pHi + (sub * 16 + rr) * 32 + qd * 8;
            ushort_t* dstl = pLo + (sub * 16 + rr) * 32 + qd * 8;
            if (act) {
                float rowv[3][10];
                #pragma unroll
                for (int dr = 0; dr < 3; ++dr) {
                    const int wr = rr - 1 + dr;
                    const int sw = s0 - 1 + wr;
                    const bool vw = (sw >= 0) && (sw <= S_LEN - 1);
                    float4 v0 = *(const float4*)&dpS[slotC][wr][c0];
                    float4 v1 = *(const float4*)&dpS[slotC][wr][c0 + 4];
                    float lf = (cg > 0)  ? dpS[slotC][wr][c0 - 1]
                                         : ((c > 0)       ? dpS[slotL][wr][CH - 1] : 0.f);
                    float rg = (cg < 15) ? dpS[slotC][wr][c0 + 8]
                                         : ((c < NCH - 1) ? dpS[slotR][wr][0]      : 0.f);
                    rowv[dr][0] = vw ? lf   : 0.f;
                    rowv[dr][1] = vw ? v0.x : 0.f;
                    rowv[dr][2] = vw ? v0.y : 0.f;
                    rowv[dr][3] = vw ? v0.z : 0.f;
                    rowv[dr][4] = vw ? v0.w : 0.f;
                    rowv[dr][5] = vw ? v1.x : 0.f;
                    rowv[dr][6] = vw ? v1.y : 0.f;
                    rowv[dr][7] = vw ? v1.z : 0.f;
                    rowv[dr][8] = vw ? v1.w : 0.f;
                    rowv[dr][9] = vw ? rg   : 0.f;
                }
                const int* mrow = mask + ((size_t)b * S_LEN + (s0 - 1 + rr)) * S_LEN + c * CH + c0;
                const int4 mk0 = *(const int4*)(mrow);
                const int4 mk1 = *(const int4*)(mrow + 4);
                const int mk[8] = {mk0.x, mk0.y, mk0.z, mk0.w, mk1.x, mk1.y, mk1.z, mk1.w};
                float pre[8];
                #pragma unroll
                for (int i = 0; i < 8; ++i) {
                    float p = lb;
                    #pragma unroll
                    for (int f = 0; f < 4; ++f) {
                        float cv = cb[f];
                        #pragma unroll
                        for (int dr = 0; dr < 3; ++dr)
                            #pragma unroll
                            for (int dc = 0; dc < 3; ++dc)
                                cv = fmaf(w[f * 9 + dr * 3 + dc], rowv[dr][i + dc], cv);
                        float a2 = cv > 0.f ? cv : 0.01f * cv;
                        p = fmaf(lw[f], a2, p);
                    }
                    pre[i] = (mk[i] == 0) ? -1e30f : p;
                }
                float cmax = pre[0];
                #pragma unroll
                for (int i = 1; i < 8; ++i) cmax = fmaxf(cmax, pre[i]);
                #pragma unroll
                for (int off = 1; off < 16; off <<= 1)
                    cmax = fmaxf(cmax, __shfl_xor(cmax, off));
                const float m_old = mS[rr];
                const float m_new = fmaxf(m_old, cmax);
                const float alpha = __expf(m_old - m_new);
                float pv[8], psum = 0.f;
                #pragma unroll
                for (int i = 0; i < 8; ++i) { pv[i] = __expf(pre[i] - m_new); psum += pv[i]; }
                #pragma unroll
                for (int off = 1; off < 16; off <<= 1) psum += __shfl_xor(psum, off);
                if (cg == 0) {
                    mS[rr] = m_new;
                    aS[rr] = alpha;
                    lS[rr] = lS[rr] * alpha + psum;
                }
                ushort_t hh[8], ll[8];
                #pragma unroll
                for (int i = 0; i < 8; ++i) split1(pv[i], hh[i], ll[i]);
                short8 hv, lv;
                #pragma unroll
                for (int i = 0; i < 8; ++i) { hv[i] = (short)hh[i]; lv[i] = (short)ll[i]; }
                *(short8*)dsth = hv;
                *(short8*)dstl = lv;
            } else {
                short8 z = {0, 0, 0, 0, 0, 0, 0, 0};
                *(short8*)dsth = z;
                *(short8*)dstl = z;
            }
            __syncthreads();

            // --------------------- PV MFMA on chunk c -----------------------
            {
                const float a0 = aS[quad * 4 + 0];
                const float a1 = aS[quad * 4 + 1];
                const float a2 = aS[quad * 4 + 2];
                const float a3 = aS[quad * 4 + 3];
                O[0] *= a0; O[1] *= a1; O[2] *= a2; O[3] *= a3;
                const size_t vbase = ((size_t)bh * D_DIM + d0 + m) * S_LEN + c * CH + quad * 8;
                #pragma unroll
                for (int sb = 0; sb < 4; ++sb) {
                    short8 ph = *(const short8*)(pHi + (sb * 16 + m) * 32 + quad * 8);
                    short8 pl = *(const short8*)(pLo + (sb * 16 + m) * 32 + quad * 8);
                    short8 vh = *(const short8*)(vthi + vbase + sb * 32);
                    short8 vl = *(const short8*)(vtlo + vbase + sb * 32);
                    O = __builtin_amdgcn_mfma_f32_16x16x32_bf16(ph, vh, O, 0, 0, 0);
                    O = __builtin_amdgcn_mfma_f32_16x16x32_bf16(pl, vh, O, 0, 0, 0);
                    O = __builtin_amdgcn_mfma_f32_16x16x32_bf16(ph, vl, O, 0, 0, 0);
                }
            }
        }
        __syncthreads();
    }

    // ---------------------------- epilogue ----------------------------------
    #pragma unroll
    for (int r = 0; r < 4; ++r) {
        const int br = quad * 4 + r;
        const int s = s0 - 1 + br;
        if (br >= 1 && br <= RPB && s <= S_LEN - 1)
            out[((size_t)bh * S_LEN + s) * D_DIM + d0 + m] = O[r] / lS[br];
    }
}

extern "C" void kernel_launch(void* const* d_in, const int* in_sizes, int n_in,
                              void* d_out, int out_size, void* d_ws, size_t ws_size,
                              hipStream_t stream) {
    const float* q      = (const float*)d_in[0];
    const float* k      = (const float*)d_in[1];
    const float* v      = (const float*)d_in[2];
    const int*   mask   = (const int*)d_in[3];
    const float* conv_w = (const float*)d_in[4];
    const float* conv_b = (const float*)d_in[5];
    const float* lin_w  = (const float*)d_in[6];
    const float* lin_b  = (const float*)d_in[7];
    float* out = (float*)d_out;

    // workspace: bf16 split arrays only (2 MiB each)
    char* wsb = (char*)d_ws;
    const size_t MB = 1024 * 1024;
    ushort_t* qhi  = (ushort_t*)(wsb + 0 * MB);
    ushort_t* qlo  = (ushort_t*)(wsb + 2 * MB);
    ushort_t* khi  = (ushort_t*)(wsb + 4 * MB);
    ushort_t* klo  = (ushort_t*)(wsb + 6 * MB);
    ushort_t* vthi = (ushort_t*)(wsb + 8 * MB);
    ushort_t* vtlo = (ushort_t*)(wsb + 10 * MB);

    split_qk<<<dim3(2048), 256, 0, stream>>>(q, k, qhi, qlo, khi, klo);
    vprep<<<dim3(16, NBH), 256, 0, stream>>>(v, vthi, vtlo);
    fused_attn<<<dim3(NSB, NBH), 256, 0, stream>>>(
        qhi, qlo, khi, klo, vthi, vtlo, mask,
        conv_w, conv_b, lin_w, lin_b, out);
}

// Round 5
// 175.638 us; speedup vs baseline: 1.2397x; 1.0045x over previous
//
#include <hip/hip_runtime.h>
#include <math.h>

#define S_LEN 1024
#define D_DIM 64
#define NBH   16
#define CH    128          // t-chunk width
#define NCH   8            // chunks per row
#define RPB   14           // output rows per block (16-row tile - 2 halo)
#define NSB   74           // ceil(1024/14)

typedef unsigned short ushort_t;
typedef __attribute__((ext_vector_type(8))) short short8;   // 8 bf16 (4 VGPRs)
typedef __attribute__((ext_vector_type(4))) short short4v;  // 4 bf16 (8 B)
typedef __attribute__((ext_vector_type(4))) float f32x4;

// fp32 -> (hi, lo) bf16 pair, round-to-nearest-even.
__device__ __forceinline__ void split1(float x, ushort_t& h, ushort_t& l) {
    unsigned u = __float_as_uint(x);
    unsigned hh = (u + 0x7FFFu + ((u >> 16) & 1u)) >> 16;
    float hf = __uint_as_float(hh << 16);
    float lf = x - hf;
    unsigned ul = __float_as_uint(lf);
    unsigned hl = (ul + 0x7FFFu + ((ul >> 16) & 1u)) >> 16;
    h = (ushort_t)hh; l = (ushort_t)hl;
}

__device__ __forceinline__ void split8v(const float* __restrict__ x,
                                        short8& hi, short8& lo) {
    #pragma unroll
    for (int j = 0; j < 8; ++j) {
        ushort_t h, l;
        split1(x[j], h, l);
        hi[j] = (short)h; lo[j] = (short)l;
    }
}

// -------- Prep (merged): K hi/lo split  +  V transpose-split ----------------
// blocks [0,1024): K split (1M floats, one float4/thread)
// blocks [1024,1280): V 64x64 tile transpose + split
__global__ __launch_bounds__(256) void prep(const float* __restrict__ k,
                                            const float* __restrict__ v,
                                            ushort_t* __restrict__ khi, ushort_t* __restrict__ klo,
                                            ushort_t* __restrict__ vthi, ushort_t* __restrict__ vtlo) {
    __shared__ float Ls[64][65];
    const int tid = threadIdx.x;
    if (blockIdx.x < 1024) {
        const int idx = blockIdx.x * 256 + tid;
        float4 x = *(const float4*)(k + (size_t)idx * 4);
        ushort_t h[4], l[4];
        split1(x.x, h[0], l[0]); split1(x.y, h[1], l[1]);
        split1(x.z, h[2], l[2]); split1(x.w, h[3], l[3]);
        short4v hv = {(short)h[0], (short)h[1], (short)h[2], (short)h[3]};
        short4v lv = {(short)l[0], (short)l[1], (short)l[2], (short)l[3]};
        *(short4v*)(khi + (size_t)idx * 4) = hv;
        *(short4v*)(klo + (size_t)idx * 4) = lv;
    } else {
        const int bx = blockIdx.x - 1024;
        const int tt = bx & 15, bh = bx >> 4;
        const float* vb = v + ((size_t)bh * S_LEN + tt * 64) * D_DIM;
        #pragma unroll
        for (int p = 0; p < 4; ++p) {
            int idx = p * 1024 + tid * 4;
            int r = idx >> 6, c = idx & 63;
            float4 x = *(const float4*)(vb + r * 64 + c);
            Ls[r][c] = x.x; Ls[r][c+1] = x.y; Ls[r][c+2] = x.z; Ls[r][c+3] = x.w;
        }
        __syncthreads();
        const int d = tid >> 2, c0 = (tid & 3) * 16;
        ushort_t hi[16], lo[16];
        #pragma unroll
        for (int j = 0; j < 16; ++j) split1(Ls[c0 + j][d], hi[j], lo[j]);
        size_t ob = ((size_t)bh * D_DIM + d) * S_LEN + tt * 64 + c0;
        *(short8*)(vthi + ob)     = *(short8*)(hi);
        *(short8*)(vthi + ob + 8) = *(short8*)(hi + 8);
        *(short8*)(vtlo + ob)     = *(short8*)(lo);
        *(short8*)(vtlo + ob + 8) = *(short8*)(lo + 8);
    }
}

// ------------------ Fused: QK^T -> conv -> online softmax -> PV --------------
// grid (74 s-tiles, 16 bh), block 256 = 4 waves.
// dpS chunk layout: halo-padded, data col t at index t+1; col0/col129 = halos.
// Pipeline at iteration j: QK(j) | barrier | PV(j-2) + conv(j-1) | barrier
__global__ __launch_bounds__(256) void fused_attn(
    const float* __restrict__ q,
    const ushort_t* __restrict__ khi, const ushort_t* __restrict__ klo,
    const ushort_t* __restrict__ vthi, const ushort_t* __restrict__ vtlo,
    const int* __restrict__ mask,
    const float* __restrict__ conv_w, const float* __restrict__ conv_b,
    const float* __restrict__ lin_w, const float* __restrict__ lin_b,
    float* __restrict__ out)
{
    __shared__ float dpS[2][16][132];        // 2-slot ring, halo-padded (16.9 KB)
    __shared__ ushort_t pHi[2][16 * 128];    // P bf16 hi, A-frag layout, 2 slots (8 KB)
    __shared__ ushort_t pLo[2][16 * 128];    // P bf16 lo (8 KB)
    __shared__ float mS[16], lS[16];
    __shared__ float aBuf[2][16];            // per-chunk alpha, 2 slots

    const int bs = blockIdx.x, bh = blockIdx.y;
    const int s0 = bs * RPB;
    const int b  = bh >> 3;
    const int tid = threadIdx.x;
    const int wave = tid >> 6, lane = tid & 63;
    const int m = lane & 15, quad = lane >> 4;

    if (tid < 16) { mS[tid] = -1e30f; lS[tid] = 0.f; }

    // conv params (uniform addresses -> scalar loads)
    float w[36];
    #pragma unroll
    for (int i = 0; i < 36; ++i) w[i] = conv_w[i];
    float cb[4], lw[4];
    #pragma unroll
    for (int f = 0; f < 4; ++f) { cb[f] = conv_b[f]; lw[f] = lin_w[f]; }
    const float lb = lin_b[0];

    // A fragments: Q rows s0-1+m, fp32 load + in-register split
    const int sA = s0 - 1 + m;
    const int sQ = sA < 0 ? 0 : (sA > S_LEN - 1 ? S_LEN - 1 : sA);
    const float* qp = q + ((size_t)bh * S_LEN + sQ) * D_DIM + quad * 8;
    float qa[16];
    *(float4*)(qa + 0)  = *(const float4*)(qp + 0);
    *(float4*)(qa + 4)  = *(const float4*)(qp + 4);
    *(float4*)(qa + 8)  = *(const float4*)(qp + 32);
    *(float4*)(qa + 12) = *(const float4*)(qp + 36);
    short8 ahi0, alo0, ahi1, alo1;
    split8v(qa + 0, ahi0, alo0);
    split8v(qa + 8, ahi1, alo1);

    // conv-phase mapping: row rr, col-group cg (8 outputs each)
    const int rr = tid >> 4, cg = tid & 15, c0 = cg * 8;
    const bool act = (rr >= 1) && (rr <= RPB) && (s0 - 1 + rr <= S_LEN - 1);
    const int subP = cg >> 2, qdP = cg & 3;

    const int d0 = wave * 16;                // PV: wave handles d in [d0,d0+16)
    f32x4 O = {0.f, 0.f, 0.f, 0.f};

    for (int j = 0; j <= NCH + 1; ++j) {
        // ---------------- QK chunk j -> slot j&1 ----------------------------
        if (j < NCH) {
            const int slot = j & 1;
            // left halo of this slot = prev chunk's last col (or 0 for j==0)
            if (tid < 16) dpS[slot][tid][0] = j ? dpS[slot ^ 1][tid][128] : 0.f;
            #pragma unroll
            for (int ct = 0; ct < 2; ++ct) {
                const int t0 = j * CH + wave * 32 + ct * 16;
                const size_t kb = ((size_t)bh * S_LEN + t0 + m) * D_DIM + quad * 8;
                short8 bhi0 = *(const short8*)(khi + kb);
                short8 bhi1 = *(const short8*)(khi + kb + 32);
                short8 blo0 = *(const short8*)(klo + kb);
                short8 blo1 = *(const short8*)(klo + kb + 32);
                f32x4 acc = {0.f, 0.f, 0.f, 0.f};
                acc = __builtin_amdgcn_mfma_f32_16x16x32_bf16(ahi0, bhi0, acc, 0, 0, 0);
                acc = __builtin_amdgcn_mfma_f32_16x16x32_bf16(ahi0, blo0, acc, 0, 0, 0);
                acc = __builtin_amdgcn_mfma_f32_16x16x32_bf16(alo0, bhi0, acc, 0, 0, 0);
                acc = __builtin_amdgcn_mfma_f32_16x16x32_bf16(ahi1, bhi1, acc, 0, 0, 0);
                acc = __builtin_amdgcn_mfma_f32_16x16x32_bf16(ahi1, blo1, acc, 0, 0, 0);
                acc = __builtin_amdgcn_mfma_f32_16x16x32_bf16(alo1, bhi1, acc, 0, 0, 0);
                const int col = wave * 32 + ct * 16 + m;
                #pragma unroll
                for (int r = 0; r < 4; ++r) {
                    const int br = quad * 4 + r;
                    const int s  = s0 - 1 + br;
                    const float val = (s >= 0 && s < S_LEN) ? acc[r] * 0.125f : 0.f;
                    dpS[slot][br][col + 1] = val;
                    // chunk j col 0 doubles as the right halo of the prev slot
                    if (ct == 0 && wave == 0 && m == 0)
                        dpS[slot ^ 1][br][129] = val;
                }
            }
        } else if (j == NCH) {
            // right halo of last chunk (cols >= 1024 are zero-pad)
            if (tid < 16) dpS[(NCH - 1) & 1][tid][129] = 0.f;
        }
        __syncthreads();

        // ---------------- PV on chunk j-2 (reads pP[(j-2)&1]) ---------------
        if (j >= 2) {
            const int c2 = j - 2, p2 = c2 & 1;
            #pragma unroll
            for (int r = 0; r < 4; ++r) O[r] *= aBuf[p2][quad * 4 + r];
            const size_t vbase = ((size_t)bh * D_DIM + d0 + m) * S_LEN + c2 * CH + quad * 8;
            #pragma unroll
            for (int sb = 0; sb < 4; ++sb) {
                short8 ph = *(const short8*)(&pHi[p2][(sb * 16 + m) * 32 + quad * 8]);
                short8 pl = *(const short8*)(&pLo[p2][(sb * 16 + m) * 32 + quad * 8]);
                short8 vh = *(const short8*)(vthi + vbase + sb * 32);
                short8 vl = *(const short8*)(vtlo + vbase + sb * 32);
                O = __builtin_amdgcn_mfma_f32_16x16x32_bf16(ph, vh, O, 0, 0, 0);
                O = __builtin_amdgcn_mfma_f32_16x16x32_bf16(pl, vh, O, 0, 0, 0);
                O = __builtin_amdgcn_mfma_f32_16x16x32_bf16(ph, vl, O, 0, 0, 0);
            }
        }

        // ---------------- conv + mask + online softmax on chunk j-1 ---------
        if (j >= 1 && j <= NCH) {
            const int c = j - 1, pc = c & 1, slotC = c & 1;
            ushort_t* dsth = &pHi[pc][(subP * 16 + rr) * 32 + qdP * 8];
            ushort_t* dstl = &pLo[pc][(subP * 16 + rr) * 32 + qdP * 8];
            if (act) {
                float vv[3][10];
                #pragma unroll
                for (int dr = 0; dr < 3; ++dr) {
                    const float* rp = &dpS[slotC][rr - 1 + dr][c0];
                    float4 a0 = *(const float4*)(rp);
                    float4 a1 = *(const float4*)(rp + 4);
                    vv[dr][0] = a0.x; vv[dr][1] = a0.y; vv[dr][2] = a0.z; vv[dr][3] = a0.w;
                    vv[dr][4] = a1.x; vv[dr][5] = a1.y; vv[dr][6] = a1.z; vv[dr][7] = a1.w;
                    vv[dr][8] = rp[8]; vv[dr][9] = rp[9];
                }
                const int* mrow = mask + ((size_t)b * S_LEN + (s0 - 1 + rr)) * S_LEN + c * CH + c0;
                const int4 mk0 = *(const int4*)(mrow);
                const int4 mk1 = *(const int4*)(mrow + 4);
                const int mk[8] = {mk0.x, mk0.y, mk0.z, mk0.w, mk1.x, mk1.y, mk1.z, mk1.w};
                float pre[8];
                #pragma unroll
                for (int i = 0; i < 8; ++i) {
                    float p = lb;
                    #pragma unroll
                    for (int f = 0; f < 4; ++f) {
                        float cv = cb[f];
                        #pragma unroll
                        for (int dr = 0; dr < 3; ++dr) {
                            cv = fmaf(w[f * 9 + dr * 3 + 0], vv[dr][i],     cv);
                            cv = fmaf(w[f * 9 + dr * 3 + 1], vv[dr][i + 1], cv);
                            cv = fmaf(w[f * 9 + dr * 3 + 2], vv[dr][i + 2], cv);
                        }
                        float a2 = fmaxf(cv, 0.f) + 0.01f * fminf(cv, 0.f);
                        p = fmaf(lw[f], a2, p);
                    }
                    pre[i] = mk[i] ? p : -1e30f;
                }
                float cmax = pre[0];
                #pragma unroll
                for (int i = 1; i < 8; ++i) cmax = fmaxf(cmax, pre[i]);
                #pragma unroll
                for (int off = 1; off < 16; off <<= 1)
                    cmax = fmaxf(cmax, __shfl_xor(cmax, off));
                const float m_old = mS[rr];
                const float m_new = fmaxf(m_old, cmax);
                const float alpha = __expf(m_old - m_new);
                float pv[8], psum = 0.f;
                #pragma unroll
                for (int i = 0; i < 8; ++i) { pv[i] = __expf(pre[i] - m_new); psum += pv[i]; }
                #pragma unroll
                for (int off = 1; off < 16; off <<= 1) psum += __shfl_xor(psum, off);
                if (cg == 0) {
                    mS[rr] = m_new;
                    lS[rr] = lS[rr] * alpha + psum;
                    aBuf[pc][rr] = alpha;
                }
                ushort_t hh[8], ll[8];
                #pragma unroll
                for (int i = 0; i < 8; ++i) split1(pv[i], hh[i], ll[i]);
                short8 hv, lv;
                #pragma unroll
                for (int i = 0; i < 8; ++i) { hv[i] = (short)hh[i]; lv[i] = (short)ll[i]; }
                *(short8*)dsth = hv;
                *(short8*)dstl = lv;
            } else {
                short8 z = {0, 0, 0, 0, 0, 0, 0, 0};
                *(short8*)dsth = z;
                *(short8*)dstl = z;
                if (cg == 0) aBuf[pc][rr] = 1.f;
            }
        }
        __syncthreads();
    }

    // ---------------------------- epilogue ----------------------------------
    #pragma unroll
    for (int r = 0; r < 4; ++r) {
        const int br = quad * 4 + r;
        const int s = s0 - 1 + br;
        if (br >= 1 && br <= RPB && s <= S_LEN - 1)
            out[((size_t)bh * S_LEN + s) * D_DIM + d0 + m] = O[r] / lS[br];
    }
}

extern "C" void kernel_launch(void* const* d_in, const int* in_sizes, int n_in,
                              void* d_out, int out_size, void* d_ws, size_t ws_size,
                              hipStream_t stream) {
    const float* q      = (const float*)d_in[0];
    const float* k      = (const float*)d_in[1];
    const float* v      = (const float*)d_in[2];
    const int*   mask   = (const int*)d_in[3];
    const float* conv_w = (const float*)d_in[4];
    const float* conv_b = (const float*)d_in[5];
    const float* lin_w  = (const float*)d_in[6];
    const float* lin_b  = (const float*)d_in[7];
    float* out = (float*)d_out;

    char* wsb = (char*)d_ws;
    const size_t MB = 1024 * 1024;
    ushort_t* khi  = (ushort_t*)(wsb + 0 * MB);
    ushort_t* klo  = (ushort_t*)(wsb + 2 * MB);
    ushort_t* vthi = (ushort_t*)(wsb + 4 * MB);
    ushort_t* vtlo = (ushort_t*)(wsb + 6 * MB);

    prep<<<dim3(1280), 256, 0, stream>>>(k, v, khi, klo, vthi, vtlo);
    fused_attn<<<dim3(NSB, NBH), 256, 0, stream>>>(
        q, khi, klo, vthi, vtlo, mask,
        conv_w, conv_b, lin_w, lin_b, out);
}